// Round 16
// baseline (812.701 us; speedup 1.0000x reference)
//
#include <hip/hip_runtime.h>
#include <hip/hip_bf16.h>
#include <cstdint>

namespace {

constexpr int BS   = 2048;
constexpr int DIM  = 256;
constexpr int K    = 3000;
constexpr int K4   = K / 4;        // 750
constexpr int KP   = 3008;         // padded row stride (bf16 matrix)
constexpr int KP4  = KP / 4;       // 752
constexpr int KB2  = 3072;         // padded proto rows for swizzled B'
constexpr int QL   = 3840;
constexpr int NTOT = QL + BS;      // 5888
constexpr int N2   = 2 * BS;       // 4096
constexpr int NDBLK = N2 * 6 / 4;  // 6144
constexpr int RS   = 8;            // rows per sink block
constexpr int NSB  = NTOT / RS;    // 736 sink blocks per crop
constexpr float TEMP = 0.2f;
constexpr float INV_EPS = 20.0f;
constexpr float KF = 3000.0f;

// ws layout (float indices)
constexpr size_t OFF_M    = 0;                               // 2 crops of NTOT*KP ushorts
constexpr size_t OFF_S    = OFF_M + (size_t)NTOT * KP;       // 6*KP (S1..S3 x2 crops)
constexpr size_t OFF_OFFA = OFF_S + 6 * KP;                  // 3072 ints
constexpr size_t OFF_HQ   = OFF_OFFA + 3072;                 // N2 ints
constexpr size_t OFF_NQ   = OFF_HQ + N2;                     // N2*6 ints
constexpr size_t OFF_CCP  = OFF_NQ + (size_t)N2 * 6;         // BS
constexpr size_t OFF_PSP  = OFF_CCP + BS;                    // BS
constexpr size_t OFF_BUCKET = OFF_PSP + BS;                  // N2
constexpr size_t OFF_PART = OFF_BUCKET + N2;                 // NDBLK
constexpr size_t OFF_CVT  = ((OFF_PART + NDBLK + 15) / 16) * 16;
constexpr size_t OFF_OUTC = OFF_CVT + (size_t)(2 * QL + KB2) * DIM / 2;

using bf16x8 = __attribute__((ext_vector_type(8))) short;
using f32x4  = __attribute__((ext_vector_type(4))) float;
typedef unsigned int uint32;

__device__ __forceinline__ float wave_sum(float v) {
#pragma unroll
  for (int off = 32; off > 0; off >>= 1) v += __shfl_down(v, off, 64);
  return v;
}
__device__ __forceinline__ float wave_max_all(float v) {
#pragma unroll
  for (int off = 32; off > 0; off >>= 1) v = fmaxf(v, __shfl_xor(v, off, 64));
  return v;
}
__device__ __forceinline__ uint32 wave_min_u32_all(uint32 v) {
#pragma unroll
  for (int off = 32; off > 0; off >>= 1) {
    uint32 o = __shfl_xor(v, off, 64);
    v = o < v ? o : v;
  }
  return v;
}
__device__ __forceinline__ uint32 wave_max_u32(uint32 v) {
#pragma unroll
  for (int off = 32; off > 0; off >>= 1) {
    uint32 o = __shfl_down(v, off, 64);
    v = o > v ? o : v;
  }
  return v;
}
__device__ __forceinline__ uint32 fmono(float f) {
  uint32 u = __float_as_uint(f);
  return (u & 0x80000000u) ? ~u : (u | 0x80000000u);
}
__device__ __forceinline__ float bf2f(short s) {
  return __uint_as_float(((uint32)(unsigned short)s) << 16);
}
__device__ __forceinline__ ushort f2bf(float f) {
  __hip_bfloat16 b = __float2bfloat16(f);
  return *reinterpret_cast<ushort*>(&b);
}
// swizzled fragment index: (row, kq) -> ushort offset within A'/B'
__device__ __forceinline__ size_t frag_idx(int row, int kq) {
  int l = (row & 15) | (((kq >> 3) & 3) << 4);
  return ((size_t)((row >> 4) * 8 + (kq >> 5)) * 64 + l) * 8 + (kq & 7);
}

// -------- fused preprocessing: swizzle-convert queue+proto to bf16 fragments,
//          zero-pad B', normalize emb + pos dot --------
__global__ __launch_bounds__(256) void k_pre(
    const float* __restrict__ queue, const float* __restrict__ proto,
    const float* __restrict__ emb, ushort* __restrict__ cvt,
    float* __restrict__ outc, float* __restrict__ pospart) {
  const int bid = blockIdx.x, tid = threadIdx.x;
  if (bid < 1920) {                       // queue: 2*QL*DIM/4 float4s, swizzled
    int i = bid * 256 + tid;
    int row = i >> 6;
    int kq = (i & 63) * 4;
    float4 v = reinterpret_cast<const float4*>(queue)[i];
    ushort4 h;
    h.x = f2bf(v.x); h.y = f2bf(v.y); h.z = f2bf(v.z); h.w = f2bf(v.w);
    *reinterpret_cast<ushort4*>(&cvt[frag_idx(row, kq)]) = h;
  } else if (bid < 2670) {                // proto: K*DIM/4 float4s, swizzled
    int i = (bid - 1920) * 256 + tid;
    int row = i >> 6;
    int kq = (i & 63) * 4;
    float4 v = reinterpret_cast<const float4*>(proto)[i];
    ushort4 h;
    h.x = f2bf(v.x); h.y = f2bf(v.y); h.z = f2bf(v.z); h.w = f2bf(v.w);
    *reinterpret_cast<ushort4*>(&cvt[(size_t)2 * QL * DIM + frag_idx(row, kq)]) = h;
  } else if (bid < 2688) {                // zero-pad B' rows 3000..3071
    int i = (bid - 2670) * 256 + tid;
    int row = 3000 + (i >> 6);
    int kq = (i & 63) * 4;
    *reinterpret_cast<ushort4*>(&cvt[(size_t)2 * QL * DIM + frag_idx(row, kq)]) =
        make_ushort4(0, 0, 0, 0);
  } else {                                // normpos: 2048 blocks
    __shared__ float sa[4], sb[4], sd[4];
    __shared__ float na, nb;
    const int j = bid - 2688, t = tid;
    float za = emb[(size_t)(BS + j) * DIM + t] / TEMP;
    float zb = emb[(size_t)j * DIM + t] / TEMP;
    float ra = wave_sum(za * za);
    float rb = wave_sum(zb * zb);
    if ((t & 63) == 0) { sa[t >> 6] = ra; sb[t >> 6] = rb; }
    __syncthreads();
    if (t == 0) {
      na = sqrtf(sa[0] + sa[1] + sa[2] + sa[3]);
      nb = sqrtf(sb[0] + sb[1] + sb[2] + sb[3]);
    }
    __syncthreads();
    float oa = za / na, ob = zb / nb;
    outc[(size_t)j * DIM + t] = oa;
    outc[(size_t)(BS + j) * DIM + t] = ob;
    float d = wave_sum(oa * ob);
    if ((t & 63) == 0) sd[t >> 6] = d;
    __syncthreads();
    if (t == 0) pospart[j] = sd[0] + sd[1] + sd[2] + sd[3];
  }
}

// -------- fused: both crops' GEMM (barrier-free, coalesced swizzled fragment loads)
//          + initsample --------
__global__ __launch_bounds__(256) void k_gemm_init(
    const ushort* __restrict__ cvt, const float* __restrict__ output,
    ushort* __restrict__ M2, float* __restrict__ S) {
  __shared__ ushort tile64[64][136] __attribute__((aligned(16)));
  const int bid = blockIdx.x;
  const int tid = threadIdx.x;
  if (bid < 1440) {
    const int crop = bid / 720, rem = bid % 720;
    const int bn0 = (rem % 24) * 128;
    const int bm0 = (rem / 24) * 128;
    const ushort* Ap = cvt + (size_t)crop * QL * DIM;
    const ushort* Bp = cvt + (size_t)2 * QL * DIM;
    ushort* M = M2 + (size_t)crop * NTOT * KP;
    float* S1 = S + (size_t)crop * 3 * KP;
    const int wid  = tid >> 6, lane = tid & 63;
    const int wm0  = (wid >> 1) * 64, wn0 = (wid & 1) * 64;
    const int ln15 = lane & 15, lq = lane >> 4;
    const int rbw = (bm0 >> 4) + (wm0 >> 4);
    const int cbw = (bn0 >> 4) + (wn0 >> 4);

    f32x4 acc[4][4] = {};
#pragma unroll
    for (int kk = 0; kk < 8; ++kk) {
      bf16x8 a[4], b[4];
#pragma unroll
      for (int i = 0; i < 4; ++i)
        a[i] = *reinterpret_cast<const bf16x8*>(
            &Ap[(((size_t)(rbw + i)) * 8 + kk) * 512 + lane * 8]);
#pragma unroll
      for (int j = 0; j < 4; ++j)
        b[j] = *reinterpret_cast<const bf16x8*>(
            &Bp[(((size_t)(cbw + j)) * 8 + kk) * 512 + lane * 8]);
#pragma unroll
      for (int i = 0; i < 4; ++i)
#pragma unroll
        for (int j = 0; j < 4; ++j)
          acc[i][j] = __builtin_amdgcn_mfma_f32_16x16x32_bf16(a[i], b[j], acc[i][j], 0, 0, 0);
    }

    // epilogue: two 64-row halves through tile64
    const int rw = tid >> 4;
    const int c8 = (tid & 15) * 8;
    const bool colOk = (bn0 + c8) < KP;
#pragma unroll
    for (int h = 0; h < 2; ++h) {
      if ((wid >> 1) == h) {
#pragma unroll
        for (int j = 0; j < 4; ++j) {
          int col = bn0 + wn0 + j * 16 + ln15;
          bool valid = col < K;
          float csum = 0.f;
#pragma unroll
          for (int i = 0; i < 4; ++i) {
            int rowb = i * 16 + lq * 4;
#pragma unroll
            for (int r = 0; r < 4; ++r) {
              float q = valid ? __expf(acc[i][j][r] * INV_EPS) : 0.f;
              tile64[rowb + r][wn0 + j * 16 + ln15] = f2bf(q);
              csum += q;
            }
          }
          csum += __shfl_xor(csum, 16, 64);
          csum += __shfl_xor(csum, 32, 64);
          if (lane < 16 && valid) atomicAdd(&S1[col], csum);
        }
      }
      __syncthreads();
      if (colOk) {
#pragma unroll
        for (int pass = 0; pass < 4; ++pass) {
          int row = pass * 16 + rw;
          *reinterpret_cast<bf16x8*>(&M[(size_t)(bm0 + h * 64 + row) * KP + bn0 + c8]) =
              *reinterpret_cast<const bf16x8*>(&tile64[row][c8]);
        }
      }
      __syncthreads();
    }
  } else {
    const int id2 = bid - 1440;
    const int crop = id2 / 384, rem = id2 % 384;
    const float* outCrop = output + (size_t)crop * BS * K;
    ushort* M = M2 + (size_t)crop * NTOT * KP;
    float* S1 = S + (size_t)crop * 3 * KP;
    int k4 = (rem % 3) * 256 + tid;
    int r0 = (rem / 3) * 16;
    if (k4 >= KP4) return;
    bool pad = k4 >= K4;
    float ax = 0.f, ay = 0.f, az = 0.f, aw = 0.f;
    for (int rr = 0; rr < 16; ++rr) {
      int row = r0 + rr;
      ushort4 w = make_ushort4(0, 0, 0, 0);
      if (!pad) {
        float4 x = reinterpret_cast<const float4*>(outCrop + (size_t)row * K)[k4];
        float ex = __expf(x.x * INV_EPS), ey = __expf(x.y * INV_EPS),
              ez = __expf(x.z * INV_EPS), ew = __expf(x.w * INV_EPS);
        ax += ex; ay += ey; az += ez; aw += ew;
        w.x = f2bf(ex); w.y = f2bf(ey); w.z = f2bf(ez); w.w = f2bf(ew);
      }
      reinterpret_cast<ushort4*>(M + (size_t)(QL + row) * KP)[k4] = w;
    }
    if (!pad) {
      atomicAdd(&S1[k4 * 4 + 0], ax);
      atomicAdd(&S1[k4 * 4 + 1], ay);
      atomicAdd(&S1[k4 * 4 + 2], az);
      atomicAdd(&S1[k4 * 4 + 3], aw);
    }
  }
}

// -------- fused sinkhorn iteration: ONE M read -> rowsums (v) AND colsums (S_out) --------
// 384 threads, 8 rows/block; thread t owns cols [8t, 8t+8). mm[8] = 32 VGPRs (no spill).
__global__ __launch_bounds__(384) void k_sink(
    const ushort* __restrict__ M2, float* __restrict__ S, int which) {
  __shared__ float red[RS][6];
  __shared__ float vsh[RS];
  const int tid = threadIdx.x;
  const int lane = tid & 63, wv = tid >> 6;
  const int crop = blockIdx.x >= NSB ? 1 : 0;
  const int r0 = (blockIdx.x - crop * NSB) * RS;
  const ushort* Mc = M2 + (size_t)crop * NTOT * KP;
  const float* S_in = S + (size_t)crop * 3 * KP + (size_t)which * KP;
  float* S_out = S + (size_t)crop * 3 * KP + (size_t)(which + 1) * KP;
  const bool actL = tid < 376;           // cols 8t..8t+7 exist in padded M
  const bool actU = tid < 375;           // cols < 3000 (real classes)
  const int c0 = tid * 8;

  float u[8];
#pragma unroll
  for (int e = 0; e < 8; ++e) u[e] = 0.f;
  if (actU) {
    float4 s0 = reinterpret_cast<const float4*>(S_in)[tid * 2];
    float4 s1 = reinterpret_cast<const float4*>(S_in)[tid * 2 + 1];
    u[0] = 1.0f / (KF * s0.x); u[1] = 1.0f / (KF * s0.y);
    u[2] = 1.0f / (KF * s0.z); u[3] = 1.0f / (KF * s0.w);
    u[4] = 1.0f / (KF * s1.x); u[5] = 1.0f / (KF * s1.y);
    u[6] = 1.0f / (KF * s1.z); u[7] = 1.0f / (KF * s1.w);
  }

  bf16x8 mm[RS];
  if (actL) {
#pragma unroll
    for (int r = 0; r < RS; ++r)
      mm[r] = *reinterpret_cast<const bf16x8*>(&Mc[(size_t)(r0 + r) * KP + c0]);
  }

  // phase 1: row sums with u -> v
#pragma unroll
  for (int r = 0; r < RS; ++r) {
    float s = 0.f;
    if (actL) {
#pragma unroll
      for (int e = 0; e < 8; ++e) s += bf2f(mm[r][e]) * u[e];
    }
    s = wave_sum(s);
    if (lane == 0) red[r][wv] = s;
  }
  __syncthreads();
  if (tid < RS) {
    float t = red[tid][0] + red[tid][1] + red[tid][2] +
              red[tid][3] + red[tid][4] + red[tid][5];
    vsh[tid] = 1.0f / ((float)NTOT * t);
  }
  __syncthreads();

  // phase 2: column partials weighted by v -> S_out atomics
  if (actL) {
    float acc8[8];
#pragma unroll
    for (int e = 0; e < 8; ++e) acc8[e] = 0.f;
#pragma unroll
    for (int r = 0; r < RS; ++r) {
      float vr = vsh[r];
#pragma unroll
      for (int e = 0; e < 8; ++e) acc8[e] += bf2f(mm[r][e]) * vr;
    }
#pragma unroll
    for (int e = 0; e < 8; ++e) atomicAdd(&S_out[c0 + e], acc8[e]);
  }
}

// -------- BOTH crops, one wave per row: hard_q, neg_q, cc partial (inline logu) --------
__global__ __launch_bounds__(256, 4) void k_stats_all(
    const float* __restrict__ outputAll, const float* __restrict__ S,
    int* __restrict__ hardq, int* __restrict__ negq, float* __restrict__ ccpart) {
  const int tid = threadIdx.x;
  const int lane = tid & 63, wid = tid >> 6;
  const int t = blockIdx.x * 4 + wid;
  const int crop = t >> 11;
  const float4* orow4 = reinterpret_cast<const float4*>(outputAll + (size_t)t * K);
  const float4* srow4 = reinterpret_cast<const float4*>(S + (size_t)crop * 3 * KP + 2 * KP);

  float4 o[12], l[12];
#pragma unroll
  for (int e = 0; e < 12; ++e) {
    const int g = lane + 64 * e;
    const bool valid = (e < 11) || (lane < 46);
    o[e] = valid ? orow4[g] : make_float4(0.f, 0.f, 0.f, 0.f);
  }
#pragma unroll
  for (int e = 0; e < 12; ++e) {
    const int g = lane + 64 * e;
    const bool valid = (e < 11) || (lane < 46);
    l[e] = valid ? srow4[g] : make_float4(1.f, 1.f, 1.f, 1.f);
  }

  float4 r4[12];
#pragma unroll
  for (int e = 0; e < 12; ++e) {
    r4[e].x = fmaf(o[e].x, INV_EPS, -__logf(KF * l[e].x));
    r4[e].y = fmaf(o[e].y, INV_EPS, -__logf(KF * l[e].y));
    r4[e].z = fmaf(o[e].z, INV_EPS, -__logf(KF * l[e].z));
    r4[e].w = fmaf(o[e].w, INV_EPS, -__logf(KF * l[e].w));
  }

  uint32 lmin = 0xFFFFFFFFu;
  uint32 am = 0u;
#pragma unroll
  for (int e = 0; e < 12; ++e) {
    const int g = lane + 64 * e;
    const bool valid = (e < 11) || (lane < 46);
    if (valid) {
      const int k0 = g * 4;
      uint32 mx0 = fmono(r4[e].x) & 0xFFFFF000u;
      uint32 mx1 = fmono(r4[e].y) & 0xFFFFF000u;
      uint32 mx2 = fmono(r4[e].z) & 0xFFFFF000u;
      uint32 mx3 = fmono(r4[e].w) & 0xFFFFF000u;
      uint32 k00 = mx0 | (uint32)(k0 + 0);
      uint32 k01 = mx1 | (uint32)(k0 + 1);
      uint32 k02 = mx2 | (uint32)(k0 + 2);
      uint32 k03 = mx3 | (uint32)(k0 + 3);
      uint32 n01 = k00 < k01 ? k00 : k01;
      uint32 n23 = k02 < k03 ? k02 : k03;
      uint32 nn = n01 < n23 ? n01 : n23;
      lmin = nn < lmin ? nn : lmin;
      uint32 a0 = mx0 | (uint32)(4095 - (k0 + 0));
      uint32 a1 = mx1 | (uint32)(4095 - (k0 + 1));
      uint32 a2 = mx2 | (uint32)(4095 - (k0 + 2));
      uint32 a3 = mx3 | (uint32)(4095 - (k0 + 3));
      uint32 m01 = a0 > a1 ? a0 : a1;
      uint32 m23 = a2 > a3 ? a2 : a3;
      uint32 mm = m01 > m23 ? m01 : m23;
      am = mm > am ? mm : am;
    }
  }

  uint32 t8;
  {
    uint32 c = lmin, wm = 0;
#pragma unroll
    for (int it = 0; it < 8; ++it) {
      wm = wave_min_u32_all(c);
      if (c == wm) c = 0xFFFFFFFFu;
    }
    t8 = wm;
  }

  uint32 cand[8];
#pragma unroll
  for (int c = 0; c < 8; ++c) cand[c] = 0xFFFFFFFFu;
#pragma unroll
  for (int e = 0; e < 12; ++e) {
    const int g = lane + 64 * e;
    const bool valid = (e < 11) || (lane < 46);
    if (valid) {
      const int k0 = g * 4;
      float rv[4] = {r4[e].x, r4[e].y, r4[e].z, r4[e].w};
#pragma unroll
      for (int c = 0; c < 4; ++c) {
        uint32 key = (fmono(rv[c]) & 0xFFFFF000u) | (uint32)(k0 + c);
        if (key <= t8 && key < cand[7]) {
          cand[7] = key;
#pragma unroll
          for (int q = 7; q > 0; --q)
            if (cand[q] < cand[q - 1]) { uint32 tmp = cand[q]; cand[q] = cand[q - 1]; cand[q - 1] = tmp; }
        }
      }
    }
  }

  uint32 res[6];
#pragma unroll
  for (int it = 0; it < 8; ++it) {
    uint32 head = cand[0];
    uint32 wm = wave_min_u32_all(head);
    if (it >= 2) res[it - 2] = wm;
    if (head == wm) {
      cand[0] = cand[1]; cand[1] = cand[2]; cand[2] = cand[3]; cand[3] = cand[4];
      cand[4] = cand[5]; cand[5] = cand[6]; cand[6] = cand[7]; cand[7] = 0xFFFFFFFFu;
    }
  }

  am = wave_max_u32(am);
  if (lane == 0) {
    hardq[t] = 4095 - (int)(am & 0xFFFu);
#pragma unroll
    for (int c = 0; c < 6; ++c)
      negq[(size_t)t * 6 + c] = (int)(res[c] & 0xFFFu);
  }

  if (crop == 1) {
    const float4* xrow4 = reinterpret_cast<const float4*>(outputAll + (size_t)(t - BS) * K);
    float4 x4[12];
#pragma unroll
    for (int e = 0; e < 12; ++e) {
      const int g = lane + 64 * e;
      const bool valid = (e < 11) || (lane < 46);
      x4[e] = valid ? xrow4[g] : make_float4(-3.4e38f, -3.4e38f, -3.4e38f, -3.4e38f);
    }
    float mx = -3.4e38f;
#pragma unroll
    for (int e = 0; e < 12; ++e)
      mx = fmaxf(mx, fmaxf(fmaxf(x4[e].x, x4[e].y), fmaxf(x4[e].z, x4[e].w)));
    mx = wave_max_all(mx);
    float sk = 0.f, skx = 0.f, se = 0.f;
#pragma unroll
    for (int e = 0; e < 12; ++e) {
      const bool valid = (e < 11) || (lane < 46);
      if (valid) {
        float4 rr = r4[e];
        float4 x = x4[e];
        float q;
        q = __expf(rr.x); sk += q; skx += q * x.x; se += __expf((x.x - mx) * 5.0f);
        q = __expf(rr.y); sk += q; skx += q * x.y; se += __expf((x.y - mx) * 5.0f);
        q = __expf(rr.z); sk += q; skx += q * x.z; se += __expf((x.z - mx) * 5.0f);
        q = __expf(rr.w); sk += q; skx += q * x.w; se += __expf((x.w - mx) * 5.0f);
      }
    }
    sk = wave_sum(sk); skx = wave_sum(skx); se = wave_sum(se);
    if (lane == 0) {
      float lse = mx * 5.0f + __logf(se);
      ccpart[t - BS] = skx * 5.0f / sk - lse;
    }
  }
}

// -------- fused hist + scan + scatter, single block --------
__global__ __launch_bounds__(256) void k_bucket(
    const int* __restrict__ hardq, int* __restrict__ offa_g, int* __restrict__ bucket) {
  __shared__ int cnt[3008];
  __shared__ int offa[3072];
  __shared__ int wsum[4], wpre[4];
  const int tid = threadIdx.x;
  const int lane = tid & 63, wid = tid >> 6;
  for (int t = tid; t < 3008; t += 256) cnt[t] = 0;
  __syncthreads();
  int hj[16];
#pragma unroll
  for (int t = 0; t < 16; ++t) {
    hj[t] = hardq[t * 256 + tid];
    atomicAdd(&cnt[hj[t]], 1);
  }
  __syncthreads();
  const int base = tid * 12;
  int loc[12];
  int s = 0;
#pragma unroll
  for (int t = 0; t < 12; ++t) {
    int idx = base + t;
    int cv = (idx < K) ? cnt[idx] : 0;
    loc[t] = cv; s += cv;
  }
  int vincl = s;
#pragma unroll
  for (int d = 1; d < 64; d <<= 1) {
    int t = __shfl_up(vincl, d, 64);
    if (lane >= d) vincl += t;
  }
  if (lane == 63) wsum[wid] = vincl;
  __syncthreads();
  if (tid == 0) {
    int r = 0;
#pragma unroll
    for (int w = 0; w < 4; ++w) { wpre[w] = r; r += wsum[w]; }
  }
  __syncthreads();
  int run = vincl - s + wpre[wid];
#pragma unroll
  for (int t = 0; t < 12; ++t) {
    int idx = base + t;
    if (idx < K) { offa[idx] = run; run += loc[t]; }
  }
  if (tid == 255) offa[K] = run;
  __syncthreads();
  for (int t = tid; t <= K; t += 256) offa_g[t] = offa[t];
  for (int t = tid; t < 3008; t += 256) cnt[t] = 0;
  __syncthreads();
#pragma unroll
  for (int t = 0; t < 16; ++t) {
    int c = hj[t];
    int p = atomicAdd(&cnt[c], 1);
    bucket[offa[c] + p] = t * 256 + tid;
  }
}

__global__ __launch_bounds__(256) void k_denom2(
    const float* __restrict__ outc, const int* __restrict__ negq,
    const int* __restrict__ offa, const int* __restrict__ bucket,
    float* __restrict__ partial) {
  __shared__ float s4[4];
  const int tid = threadIdx.x;
  const int wid = tid >> 6, lane = tid & 63;
  const int task = blockIdx.x * 4 + wid;
  const int i = task / 6, slot = task - i * 6;
  const int c = negq[i * 6 + slot];
  const int lo = offa[c];
  const int n = offa[c + 1] - lo;
  float acc = 0.f;
  if (n > 0) {
    const float4 a = reinterpret_cast<const float4*>(outc + (size_t)i * DIM)[lane];
    for (int m = 0; m < n; ++m) {
      int j = bucket[lo + m];
      if (j == i) continue;
      const float4 b = reinterpret_cast<const float4*>(outc + (size_t)j * DIM)[lane];
      float d = a.x * b.x + a.y * b.y + a.z * b.z + a.w * b.w;
      d = wave_sum(d);
      if (lane == 0) acc += __expf(d * 5.0f);
    }
  }
  if (lane == 0) s4[wid] = acc;
  __syncthreads();
  if (tid == 0) partial[blockIdx.x] = s4[0] + s4[1] + s4[2] + s4[3];
}

__global__ __launch_bounds__(256) void k_final(
    const float* __restrict__ partial, const float* __restrict__ ccpart,
    const float* __restrict__ pospart, float* __restrict__ out) {
  __shared__ float s4[4], c4[4], p4[4];
  const int tid = threadIdx.x;
  float s = 0.f, cc = 0.f, ps = 0.f;
  for (int m = tid; m < NDBLK; m += 256) s += partial[m];
  for (int m = tid; m < BS; m += 256) { cc += ccpart[m]; ps += pospart[m]; }
  s = wave_sum(s); cc = wave_sum(cc); ps = wave_sum(ps);
  if ((tid & 63) == 0) { int w = tid >> 6; s4[w] = s; c4[w] = cc; p4[w] = ps; }
  __syncthreads();
  if (tid == 0) {
    float denom  = s4[0] + s4[1] + s4[2] + s4[3];
    float ccsum  = c4[0] + c4[1] + c4[2] + c4[3];
    float possum = p4[0] + p4[1] + p4[2] + p4[3];
    float contrast = logf(denom) - possum / ((float)BS * TEMP);
    out[0] = contrast - 6.0f * ccsum / (float)BS;
  }
}

}  // namespace

extern "C" void kernel_launch(void* const* d_in, const int* in_sizes, int n_in,
                              void* d_out, int out_size, void* d_ws, size_t ws_size,
                              hipStream_t stream) {
  const float* queue  = (const float*)d_in[3];  // [2][QL][DIM]
  const float* proto  = (const float*)d_in[4];  // [K][DIM]
  const float* output = (const float*)d_in[5];  // [2*BS][K]
  const float* emb    = (const float*)d_in[6];  // [2*BS][DIM]
  float* ws = (float*)d_ws;
  ushort* M2   = (ushort*)(ws + OFF_M);
  float* S     = ws + OFF_S;
  int* offa    = (int*)(ws + OFF_OFFA);
  int* hardq   = (int*)(ws + OFF_HQ);
  int* negq    = (int*)(ws + OFF_NQ);
  float* ccpart = ws + OFF_CCP;
  float* pospart = ws + OFF_PSP;
  int* bucket  = (int*)(ws + OFF_BUCKET);
  float* partial = ws + OFF_PART;
  ushort* cvt  = (ushort*)(ws + OFF_CVT);
  float* outc  = ws + OFF_OUTC;
  float* out   = (float*)d_out;

  hipMemsetAsync(S, 0, 6 * KP * sizeof(float), stream);

  k_pre<<<2688 + BS, 256, 0, stream>>>(queue, proto, emb, cvt, outc, pospart);
  k_gemm_init<<<1440 + 768, 256, 0, stream>>>(cvt, output, M2, S);
  // sinkhorn: 2 fused iterations, one M read each (rowsum->v->colsum in-register)
  k_sink<<<2 * NSB, 384, 0, stream>>>(M2, S, 0);   // S1 -> S2
  k_sink<<<2 * NSB, 384, 0, stream>>>(M2, S, 1);   // S2 -> S3
  k_stats_all<<<N2 / 4, 256, 0, stream>>>(output, S, hardq, negq, ccpart);
  k_bucket<<<1, 256, 0, stream>>>(hardq, offa, bucket);
  k_denom2<<<NDBLK, 256, 0, stream>>>(outc, negq, offa, bucket, partial);
  k_final<<<1, 256, 0, stream>>>(partial, ccpart, pospart, out);
}

// Round 17
// 195.907 us; speedup vs baseline: 4.1484x; 4.1484x over previous
//
#include <hip/hip_runtime.h>
#include <hip/hip_bf16.h>
#include <cstdint>

namespace {

constexpr int BS   = 2048;
constexpr int DIM  = 256;
constexpr int K    = 3000;
constexpr int K4   = K / 4;        // 750
constexpr int KP   = 3008;         // padded row stride (bf16 matrix)
constexpr int KP4  = KP / 4;       // 752
constexpr int QL   = 3840;
constexpr int NTOT = QL + BS;      // 5888
constexpr int N2   = 2 * BS;       // 4096
constexpr int NDBLK = N2 * 6 / 4;  // 6144
constexpr int NROWG = NTOT / 128;  // 46 colsum row-groups (128 rows each)
constexpr float TEMP = 0.2f;
constexpr float INV_EPS = 20.0f;
constexpr float KF = 3000.0f;

// ws layout (float indices) — identical to round 13
constexpr size_t OFF_M    = 0;                               // 2 crops of NTOT*KP ushorts
constexpr size_t OFF_S    = OFF_M + (size_t)NTOT * KP;       // 6*KP (S1..S3 x2 crops)
constexpr size_t OFF_CNT  = OFF_S + 6 * KP;                  // 3008 ints
constexpr size_t OFF_OFFA = OFF_CNT + 3008;                  // 3072 ints
constexpr size_t OFF_CUR  = OFF_OFFA + 3072;                 // 3008 ints
constexpr size_t OFF_V    = OFF_CUR + 3008;                  // 2*NTOT
constexpr size_t OFF_HQ   = OFF_V + 2 * NTOT;                // N2 ints
constexpr size_t OFF_NQ   = OFF_HQ + N2;                     // N2*6 ints
constexpr size_t OFF_CCP  = OFF_NQ + (size_t)N2 * 6;         // BS
constexpr size_t OFF_PSP  = OFF_CCP + BS;                    // BS
constexpr size_t OFF_BUCKET = OFF_PSP + BS;                  // N2
constexpr size_t OFF_PART = OFF_BUCKET + N2;                 // NDBLK
constexpr size_t OFF_CVT  = ((OFF_PART + NDBLK + 15) / 16) * 16;
constexpr size_t OFF_OUTC = OFF_CVT + (size_t)(2 * QL + K) * DIM / 2;

using bf16x8 = __attribute__((ext_vector_type(8))) short;
using f32x4  = __attribute__((ext_vector_type(4))) float;
typedef unsigned int uint32;

__device__ __forceinline__ float wave_sum(float v) {
#pragma unroll
  for (int off = 32; off > 0; off >>= 1) v += __shfl_down(v, off, 64);
  return v;
}
__device__ __forceinline__ float wave_max_all(float v) {
#pragma unroll
  for (int off = 32; off > 0; off >>= 1) v = fmaxf(v, __shfl_xor(v, off, 64));
  return v;
}
__device__ __forceinline__ uint32 wave_min_u32_all(uint32 v) {
#pragma unroll
  for (int off = 32; off > 0; off >>= 1) {
    uint32 o = __shfl_xor(v, off, 64);
    v = o < v ? o : v;
  }
  return v;
}
__device__ __forceinline__ uint32 wave_max_u32(uint32 v) {
#pragma unroll
  for (int off = 32; off > 0; off >>= 1) {
    uint32 o = __shfl_down(v, off, 64);
    v = o > v ? o : v;
  }
  return v;
}
__device__ __forceinline__ uint32 fmono(float f) {
  uint32 u = __float_as_uint(f);
  return (u & 0x80000000u) ? ~u : (u | 0x80000000u);
}
__device__ __forceinline__ float bf2f(short s) {
  return __uint_as_float(((uint32)(unsigned short)s) << 16);
}
__device__ __forceinline__ ushort f2bf(float f) {
  __hip_bfloat16 b = __float2bfloat16(f);
  return *reinterpret_cast<ushort*>(&b);
}

// -------- fused preprocessing: convert queue+proto to bf16, normalize emb + pos dot --------
__global__ __launch_bounds__(256) void k_pre(
    const float* __restrict__ queue, const float* __restrict__ proto,
    const float* __restrict__ emb, ushort* __restrict__ cvt,
    float* __restrict__ outc, float* __restrict__ pospart) {
  const int bid = blockIdx.x, tid = threadIdx.x;
  if (bid < 1920) {
    int i = bid * 256 + tid;
    float4 v = reinterpret_cast<const float4*>(queue)[i];
    ushort4 h;
    h.x = f2bf(v.x); h.y = f2bf(v.y); h.z = f2bf(v.z); h.w = f2bf(v.w);
    reinterpret_cast<ushort4*>(cvt)[i] = h;
  } else if (bid < 2670) {
    int i = (bid - 1920) * 256 + tid;
    float4 v = reinterpret_cast<const float4*>(proto)[i];
    ushort4 h;
    h.x = f2bf(v.x); h.y = f2bf(v.y); h.z = f2bf(v.z); h.w = f2bf(v.w);
    reinterpret_cast<ushort4*>(cvt + (size_t)2 * QL * DIM)[i] = h;
  } else {
    __shared__ float sa[4], sb[4], sd[4];
    __shared__ float na, nb;
    const int j = bid - 2670, t = tid;
    float za = emb[(size_t)(BS + j) * DIM + t] / TEMP;
    float zb = emb[(size_t)j * DIM + t] / TEMP;
    float ra = wave_sum(za * za);
    float rb = wave_sum(zb * zb);
    if ((t & 63) == 0) { sa[t >> 6] = ra; sb[t >> 6] = rb; }
    __syncthreads();
    if (t == 0) {
      na = sqrtf(sa[0] + sa[1] + sa[2] + sa[3]);
      nb = sqrtf(sb[0] + sb[1] + sb[2] + sb[3]);
    }
    __syncthreads();
    float oa = za / na, ob = zb / nb;
    outc[(size_t)j * DIM + t] = oa;
    outc[(size_t)(BS + j) * DIM + t] = ob;
    float d = wave_sum(oa * ob);
    if ((t & 63) == 0) sd[t >> 6] = d;
    __syncthreads();
    if (t == 0) pospart[j] = sd[0] + sd[1] + sd[2] + sd[3];
  }
}

// -------- fused: both crops' GEMM (r13 LDS-staged, reg-prefetch) +
//          initsample (64 rows/block -> 4x fewer atomics) --------
__global__ __launch_bounds__(256) void k_gemm_init(
    const ushort* __restrict__ cvt, const float* __restrict__ output,
    ushort* __restrict__ M2, float* __restrict__ S) {
  __shared__ ushort smem[10240] __attribute__((aligned(16)));  // 20480 B
  const int bid = blockIdx.x;
  const int tid = threadIdx.x;
  if (bid < 1440) {
    ushort (*Ah)[40] = reinterpret_cast<ushort(*)[40]>(smem);
    ushort (*Bh)[40] = reinterpret_cast<ushort(*)[40]>(smem + 5120);
    ushort (*tile64)[136] = reinterpret_cast<ushort(*)[136]>(smem);
    const int crop = bid / 720, rem = bid % 720;
    const int bn0 = (rem % 24) * 128;
    const int bm0 = (rem / 24) * 128;
    const ushort* A_g = cvt + (size_t)crop * QL * DIM;
    const ushort* B_g = cvt + (size_t)2 * QL * DIM;
    ushort* M = M2 + (size_t)crop * NTOT * KP;
    float* S1 = S + (size_t)crop * 3 * KP;
    const int wid  = tid >> 6, lane = tid & 63;
    const int wm0  = (wid >> 1) * 64, wn0 = (wid & 1) * 64;
    const int ln15 = lane & 15, lq = lane >> 4;
    const int lr   = tid >> 2;
    const int lc   = (tid & 3) * 8;
    const int brow0 = (bn0 + lr >= K) ? (K - 1) : (bn0 + lr);
    const int brow1 = (bn0 + 64 + lr >= K) ? (K - 1) : (bn0 + 64 + lr);

    f32x4 acc[4][4] = {};
    bf16x8 ra0, ra1, rb0, rb1;
    ra0 = *reinterpret_cast<const bf16x8*>(&A_g[(size_t)(bm0 + lr) * DIM + lc]);
    ra1 = *reinterpret_cast<const bf16x8*>(&A_g[(size_t)(bm0 + 64 + lr) * DIM + lc]);
    rb0 = *reinterpret_cast<const bf16x8*>(&B_g[(size_t)brow0 * DIM + lc]);
    rb1 = *reinterpret_cast<const bf16x8*>(&B_g[(size_t)brow1 * DIM + lc]);

    for (int it = 0; it < 8; ++it) {
      *reinterpret_cast<bf16x8*>(&Ah[lr][lc]) = ra0;
      *reinterpret_cast<bf16x8*>(&Ah[64 + lr][lc]) = ra1;
      *reinterpret_cast<bf16x8*>(&Bh[lr][lc]) = rb0;
      *reinterpret_cast<bf16x8*>(&Bh[64 + lr][lc]) = rb1;
      __syncthreads();
      if (it < 7) {
        const int kk = (it + 1) * 32;
        ra0 = *reinterpret_cast<const bf16x8*>(&A_g[(size_t)(bm0 + lr) * DIM + kk + lc]);
        ra1 = *reinterpret_cast<const bf16x8*>(&A_g[(size_t)(bm0 + 64 + lr) * DIM + kk + lc]);
        rb0 = *reinterpret_cast<const bf16x8*>(&B_g[(size_t)brow0 * DIM + kk + lc]);
        rb1 = *reinterpret_cast<const bf16x8*>(&B_g[(size_t)brow1 * DIM + kk + lc]);
      }
      bf16x8 ah[4], bh[4];
#pragma unroll
      for (int i = 0; i < 4; ++i) {
        ah[i] = *reinterpret_cast<const bf16x8*>(&Ah[wm0 + i * 16 + ln15][lq * 8]);
        bh[i] = *reinterpret_cast<const bf16x8*>(&Bh[wn0 + i * 16 + ln15][lq * 8]);
      }
#pragma unroll
      for (int i = 0; i < 4; ++i)
#pragma unroll
        for (int j = 0; j < 4; ++j)
          acc[i][j] = __builtin_amdgcn_mfma_f32_16x16x32_bf16(ah[i], bh[j], acc[i][j], 0, 0, 0);
      __syncthreads();
    }

    // epilogue: two 64-row halves through tile64 (aliases staging LDS)
    const int rw = tid >> 4;
    const int c8 = (tid & 15) * 8;
    const bool colOk = (bn0 + c8) < KP;
#pragma unroll
    for (int h = 0; h < 2; ++h) {
      if ((wid >> 1) == h) {
#pragma unroll
        for (int j = 0; j < 4; ++j) {
          int col = bn0 + wn0 + j * 16 + ln15;
          bool valid = col < K;
          float csum = 0.f;
#pragma unroll
          for (int i = 0; i < 4; ++i) {
            int rowb = i * 16 + lq * 4;
#pragma unroll
            for (int r = 0; r < 4; ++r) {
              float q = valid ? __expf(acc[i][j][r] * INV_EPS) : 0.f;
              tile64[rowb + r][wn0 + j * 16 + ln15] = f2bf(q);
              csum += q;
            }
          }
          csum += __shfl_xor(csum, 16, 64);
          csum += __shfl_xor(csum, 32, 64);
          if (lane < 16 && valid) atomicAdd(&S1[col], csum);
        }
      }
      __syncthreads();
      if (colOk) {
#pragma unroll
        for (int pass = 0; pass < 4; ++pass) {
          int row = pass * 16 + rw;
          *reinterpret_cast<bf16x8*>(&M[(size_t)(bm0 + h * 64 + row) * KP + bn0 + c8]) =
              *reinterpret_cast<const bf16x8*>(&tile64[row][c8]);
        }
      }
      __syncthreads();
    }
  } else {
    // initsample: 64 rows per block (4x fewer atomics than r13's 16)
    const int id2 = bid - 1440;
    const int crop = id2 / 96, rem = id2 % 96;
    const float* outCrop = output + (size_t)crop * BS * K;
    ushort* M = M2 + (size_t)crop * NTOT * KP;
    float* S1 = S + (size_t)crop * 3 * KP;
    int k4 = (rem % 3) * 256 + tid;
    int r0 = (rem / 3) * 64;
    if (k4 >= KP4) return;
    bool pad = k4 >= K4;
    float ax = 0.f, ay = 0.f, az = 0.f, aw = 0.f;
    for (int rr = 0; rr < 64; ++rr) {
      int row = r0 + rr;
      ushort4 w = make_ushort4(0, 0, 0, 0);
      if (!pad) {
        float4 x = reinterpret_cast<const float4*>(outCrop + (size_t)row * K)[k4];
        float ex = __expf(x.x * INV_EPS), ey = __expf(x.y * INV_EPS),
              ez = __expf(x.z * INV_EPS), ew = __expf(x.w * INV_EPS);
        ax += ex; ay += ey; az += ez; aw += ew;
        w.x = f2bf(ex); w.y = f2bf(ey); w.z = f2bf(ez); w.w = f2bf(ew);
      }
      reinterpret_cast<ushort4*>(M + (size_t)(QL + row) * KP)[k4] = w;
    }
    if (!pad) {
      atomicAdd(&S1[k4 * 4 + 0], ax);
      atomicAdd(&S1[k4 * 4 + 1], ay);
      atomicAdd(&S1[k4 * 4 + 2], az);
      atomicAdd(&S1[k4 * 4 + 3], aw);
    }
  }
}

// -------- rowpass both crops: v[n] = 1/(NTOT * sum_k M[n][k]/(K*S_in[k])) --------
__global__ __launch_bounds__(256) void k_rowpass_both(
    const ushort* __restrict__ M2, const float* __restrict__ S, float* __restrict__ v2,
    int which) {
  __shared__ float red[4];
  const int tid = threadIdx.x;
  const int bid = blockIdx.x;
  const int crop = bid >= NTOT ? 1 : 0;
  const int n = bid - crop * NTOT;
  const ushort* row = M2 + (size_t)crop * NTOT * KP + (size_t)n * KP;
  const float* S_in = S + (size_t)crop * 3 * KP + (size_t)which * KP;
  float* v = v2 + (size_t)crop * NTOT;
  const int g1 = tid, g2 = tid + 256;
  const bool has2 = g2 < KP / 8;
  const bool pad2 = has2 && (g2 == 375);

  float ua[8], ub[8];
  {
    float4 s0 = reinterpret_cast<const float4*>(S_in)[g1 * 2];
    float4 s1 = reinterpret_cast<const float4*>(S_in)[g1 * 2 + 1];
    ua[0] = 1.0f / (KF * s0.x); ua[1] = 1.0f / (KF * s0.y);
    ua[2] = 1.0f / (KF * s0.z); ua[3] = 1.0f / (KF * s0.w);
    ua[4] = 1.0f / (KF * s1.x); ua[5] = 1.0f / (KF * s1.y);
    ua[6] = 1.0f / (KF * s1.z); ua[7] = 1.0f / (KF * s1.w);
  }
  if (has2 && !pad2) {
    float4 s0 = reinterpret_cast<const float4*>(S_in)[g2 * 2];
    float4 s1 = reinterpret_cast<const float4*>(S_in)[g2 * 2 + 1];
    ub[0] = 1.0f / (KF * s0.x); ub[1] = 1.0f / (KF * s0.y);
    ub[2] = 1.0f / (KF * s0.z); ub[3] = 1.0f / (KF * s0.w);
    ub[4] = 1.0f / (KF * s1.x); ub[5] = 1.0f / (KF * s1.y);
    ub[6] = 1.0f / (KF * s1.z); ub[7] = 1.0f / (KF * s1.w);
  } else {
#pragma unroll
    for (int e = 0; e < 8; ++e) ub[e] = 0.f;
  }

  float s = 0.f;
  {
    bf16x8 a = *reinterpret_cast<const bf16x8*>(&row[g1 * 8]);
#pragma unroll
    for (int e = 0; e < 8; ++e) s += bf2f(a[e]) * ua[e];
    if (has2) {
      bf16x8 c = *reinterpret_cast<const bf16x8*>(&row[g2 * 8]);
#pragma unroll
      for (int e = 0; e < 8; ++e) s += bf2f(c[e]) * ub[e];
    }
  }
  s = wave_sum(s);
  if ((tid & 63) == 0) red[tid >> 6] = s;
  __syncthreads();
  if (tid == 0) v[n] = 1.0f / ((float)NTOT * (red[0] + red[1] + red[2] + red[3]));
}

// -------- colsum both crops: 128 rows per block (4x fewer atomics) --------
__global__ __launch_bounds__(256) void k_colsum_both(
    const ushort* __restrict__ M2, const float* __restrict__ v2, float* __restrict__ S,
    int which) {
  __shared__ float vsh[128];
  const int tid = threadIdx.x;
  const int crop = blockIdx.y >= NROWG ? 1 : 0;
  const int yy = blockIdx.y - crop * NROWG;
  const ushort* M = M2 + (size_t)crop * NTOT * KP;
  const float* v = v2 + (size_t)crop * NTOT;
  float* S_out = S + (size_t)crop * 3 * KP + (size_t)which * KP;
  const int g = blockIdx.x * 256 + tid;
  const int n0 = yy * 128;
  if (tid < 128) vsh[tid] = v[n0 + tid];
  __syncthreads();
  if (g >= KP4) return;
  float c0 = 0.f, c1 = 0.f, c2 = 0.f, c3 = 0.f;
#pragma unroll 8
  for (int rr = 0; rr < 128; ++rr) {
    ushort4 m = reinterpret_cast<const ushort4*>(M + (size_t)(n0 + rr) * KP)[g];
    float vr = vsh[rr];
    c0 += bf2f((short)m.x) * vr;
    c1 += bf2f((short)m.y) * vr;
    c2 += bf2f((short)m.z) * vr;
    c3 += bf2f((short)m.w) * vr;
  }
  atomicAdd(&S_out[g * 4 + 0], c0);
  atomicAdd(&S_out[g * 4 + 1], c1);
  atomicAdd(&S_out[g * 4 + 2], c2);
  atomicAdd(&S_out[g * 4 + 3], c3);
}

// -------- BOTH crops, one wave per row: hard_q, neg_q, cc partial (inline logu) --------
__global__ __launch_bounds__(256, 4) void k_stats_all(
    const float* __restrict__ outputAll, const float* __restrict__ S,
    int* __restrict__ hardq, int* __restrict__ negq, float* __restrict__ ccpart) {
  const int tid = threadIdx.x;
  const int lane = tid & 63, wid = tid >> 6;
  const int t = blockIdx.x * 4 + wid;
  const int crop = t >> 11;
  const float4* orow4 = reinterpret_cast<const float4*>(outputAll + (size_t)t * K);
  const float4* srow4 = reinterpret_cast<const float4*>(S + (size_t)crop * 3 * KP + 2 * KP);

  float4 o[12], l[12];
#pragma unroll
  for (int e = 0; e < 12; ++e) {
    const int g = lane + 64 * e;
    const bool valid = (e < 11) || (lane < 46);
    o[e] = valid ? orow4[g] : make_float4(0.f, 0.f, 0.f, 0.f);
  }
#pragma unroll
  for (int e = 0; e < 12; ++e) {
    const int g = lane + 64 * e;
    const bool valid = (e < 11) || (lane < 46);
    l[e] = valid ? srow4[g] : make_float4(1.f, 1.f, 1.f, 1.f);
  }

  float4 r4[12];
#pragma unroll
  for (int e = 0; e < 12; ++e) {
    r4[e].x = fmaf(o[e].x, INV_EPS, -__logf(KF * l[e].x));
    r4[e].y = fmaf(o[e].y, INV_EPS, -__logf(KF * l[e].y));
    r4[e].z = fmaf(o[e].z, INV_EPS, -__logf(KF * l[e].z));
    r4[e].w = fmaf(o[e].w, INV_EPS, -__logf(KF * l[e].w));
  }

  uint32 lmin = 0xFFFFFFFFu;
  uint32 am = 0u;
#pragma unroll
  for (int e = 0; e < 12; ++e) {
    const int g = lane + 64 * e;
    const bool valid = (e < 11) || (lane < 46);
    if (valid) {
      const int k0 = g * 4;
      uint32 mx0 = fmono(r4[e].x) & 0xFFFFF000u;
      uint32 mx1 = fmono(r4[e].y) & 0xFFFFF000u;
      uint32 mx2 = fmono(r4[e].z) & 0xFFFFF000u;
      uint32 mx3 = fmono(r4[e].w) & 0xFFFFF000u;
      uint32 k00 = mx0 | (uint32)(k0 + 0);
      uint32 k01 = mx1 | (uint32)(k0 + 1);
      uint32 k02 = mx2 | (uint32)(k0 + 2);
      uint32 k03 = mx3 | (uint32)(k0 + 3);
      uint32 n01 = k00 < k01 ? k00 : k01;
      uint32 n23 = k02 < k03 ? k02 : k03;
      uint32 nn = n01 < n23 ? n01 : n23;
      lmin = nn < lmin ? nn : lmin;
      uint32 a0 = mx0 | (uint32)(4095 - (k0 + 0));
      uint32 a1 = mx1 | (uint32)(4095 - (k0 + 1));
      uint32 a2 = mx2 | (uint32)(4095 - (k0 + 2));
      uint32 a3 = mx3 | (uint32)(4095 - (k0 + 3));
      uint32 m01 = a0 > a1 ? a0 : a1;
      uint32 m23 = a2 > a3 ? a2 : a3;
      uint32 mm = m01 > m23 ? m01 : m23;
      am = mm > am ? mm : am;
    }
  }

  uint32 t8;
  {
    uint32 c = lmin, wm = 0;
#pragma unroll
    for (int it = 0; it < 8; ++it) {
      wm = wave_min_u32_all(c);
      if (c == wm) c = 0xFFFFFFFFu;
    }
    t8 = wm;
  }

  uint32 cand[8];
#pragma unroll
  for (int c = 0; c < 8; ++c) cand[c] = 0xFFFFFFFFu;
#pragma unroll
  for (int e = 0; e < 12; ++e) {
    const int g = lane + 64 * e;
    const bool valid = (e < 11) || (lane < 46);
    if (valid) {
      const int k0 = g * 4;
      float rv[4] = {r4[e].x, r4[e].y, r4[e].z, r4[e].w};
#pragma unroll
      for (int c = 0; c < 4; ++c) {
        uint32 key = (fmono(rv[c]) & 0xFFFFF000u) | (uint32)(k0 + c);
        if (key <= t8 && key < cand[7]) {
          cand[7] = key;
#pragma unroll
          for (int q = 7; q > 0; --q)
            if (cand[q] < cand[q - 1]) { uint32 tmp = cand[q]; cand[q] = cand[q - 1]; cand[q - 1] = tmp; }
        }
      }
    }
  }

  uint32 res[6];
#pragma unroll
  for (int it = 0; it < 8; ++it) {
    uint32 head = cand[0];
    uint32 wm = wave_min_u32_all(head);
    if (it >= 2) res[it - 2] = wm;
    if (head == wm) {
      cand[0] = cand[1]; cand[1] = cand[2]; cand[2] = cand[3]; cand[3] = cand[4];
      cand[4] = cand[5]; cand[5] = cand[6]; cand[6] = cand[7]; cand[7] = 0xFFFFFFFFu;
    }
  }

  am = wave_max_u32(am);
  if (lane == 0) {
    hardq[t] = 4095 - (int)(am & 0xFFFu);
#pragma unroll
    for (int c = 0; c < 6; ++c)
      negq[(size_t)t * 6 + c] = (int)(res[c] & 0xFFFu);
  }

  if (crop == 1) {
    const float4* xrow4 = reinterpret_cast<const float4*>(outputAll + (size_t)(t - BS) * K);
    float4 x4[12];
#pragma unroll
    for (int e = 0; e < 12; ++e) {
      const int g = lane + 64 * e;
      const bool valid = (e < 11) || (lane < 46);
      x4[e] = valid ? xrow4[g] : make_float4(-3.4e38f, -3.4e38f, -3.4e38f, -3.4e38f);
    }
    float mx = -3.4e38f;
#pragma unroll
    for (int e = 0; e < 12; ++e)
      mx = fmaxf(mx, fmaxf(fmaxf(x4[e].x, x4[e].y), fmaxf(x4[e].z, x4[e].w)));
    mx = wave_max_all(mx);
    float sk = 0.f, skx = 0.f, se = 0.f;
#pragma unroll
    for (int e = 0; e < 12; ++e) {
      const bool valid = (e < 11) || (lane < 46);
      if (valid) {
        float4 rr = r4[e];
        float4 x = x4[e];
        float q;
        q = __expf(rr.x); sk += q; skx += q * x.x; se += __expf((x.x - mx) * 5.0f);
        q = __expf(rr.y); sk += q; skx += q * x.y; se += __expf((x.y - mx) * 5.0f);
        q = __expf(rr.z); sk += q; skx += q * x.z; se += __expf((x.z - mx) * 5.0f);
        q = __expf(rr.w); sk += q; skx += q * x.w; se += __expf((x.w - mx) * 5.0f);
      }
    }
    sk = wave_sum(sk); skx = wave_sum(skx); se = wave_sum(se);
    if (lane == 0) {
      float lse = mx * 5.0f + __logf(se);
      ccpart[t - BS] = skx * 5.0f / sk - lse;
    }
  }
}

// -------- denom via class histogram --------
__global__ __launch_bounds__(256) void k_hist(
    const int* __restrict__ hardq, int* __restrict__ cnt) {
  int j = blockIdx.x * 256 + threadIdx.x;
  atomicAdd(&cnt[hardq[j]], 1);
}

__global__ __launch_bounds__(256) void k_scan(
    const int* __restrict__ cnt, int* __restrict__ offa) {
  __shared__ int wsum[4];
  __shared__ int wpre[4];
  const int tid = threadIdx.x;
  const int lane = tid & 63, wid = tid >> 6;
  const int base = tid * 12;
  int loc[12];
  int s = 0;
#pragma unroll
  for (int t = 0; t < 12; ++t) {
    int idx = base + t;
    int cv = (idx < K) ? cnt[idx] : 0;
    loc[t] = cv; s += cv;
  }
  int vincl = s;
#pragma unroll
  for (int d = 1; d < 64; d <<= 1) {
    int t = __shfl_up(vincl, d, 64);
    if (lane >= d) vincl += t;
  }
  if (lane == 63) wsum[wid] = vincl;
  __syncthreads();
  if (tid == 0) {
    int r = 0;
#pragma unroll
    for (int w = 0; w < 4; ++w) { wpre[w] = r; r += wsum[w]; }
  }
  __syncthreads();
  int run = vincl - s + wpre[wid];
#pragma unroll
  for (int t = 0; t < 12; ++t) {
    int idx = base + t;
    if (idx < K) { offa[idx] = run; run += loc[t]; }
  }
  if (tid == 255) offa[K] = run;
}

__global__ __launch_bounds__(256) void k_scatter(
    const int* __restrict__ hardq, const int* __restrict__ offa,
    int* __restrict__ cur, int* __restrict__ bucket) {
  int j = blockIdx.x * 256 + threadIdx.x;
  int c = hardq[j];
  int p = atomicAdd(&cur[c], 1);
  bucket[offa[c] + p] = j;
}

__global__ __launch_bounds__(256) void k_denom2(
    const float* __restrict__ outc, const int* __restrict__ negq,
    const int* __restrict__ offa, const int* __restrict__ bucket,
    float* __restrict__ partial) {
  __shared__ float s4[4];
  const int tid = threadIdx.x;
  const int wid = tid >> 6, lane = tid & 63;
  const int task = blockIdx.x * 4 + wid;
  const int i = task / 6, slot = task - i * 6;
  const int c = negq[i * 6 + slot];
  const int lo = offa[c];
  const int n = offa[c + 1] - lo;
  float acc = 0.f;
  if (n > 0) {
    const float4 a = reinterpret_cast<const float4*>(outc + (size_t)i * DIM)[lane];
    for (int m = 0; m < n; ++m) {
      int j = bucket[lo + m];
      if (j == i) continue;
      const float4 b = reinterpret_cast<const float4*>(outc + (size_t)j * DIM)[lane];
      float d = a.x * b.x + a.y * b.y + a.z * b.z + a.w * b.w;
      d = wave_sum(d);
      if (lane == 0) acc += __expf(d * 5.0f);
    }
  }
  if (lane == 0) s4[wid] = acc;
  __syncthreads();
  if (tid == 0) partial[blockIdx.x] = s4[0] + s4[1] + s4[2] + s4[3];
}

__global__ __launch_bounds__(256) void k_final(
    const float* __restrict__ partial, const float* __restrict__ ccpart,
    const float* __restrict__ pospart, float* __restrict__ out) {
  __shared__ float s4[4], c4[4], p4[4];
  const int tid = threadIdx.x;
  float s = 0.f, cc = 0.f, ps = 0.f;
  for (int m = tid; m < NDBLK; m += 256) s += partial[m];
  for (int m = tid; m < BS; m += 256) { cc += ccpart[m]; ps += pospart[m]; }
  s = wave_sum(s); cc = wave_sum(cc); ps = wave_sum(ps);
  if ((tid & 63) == 0) { int w = tid >> 6; s4[w] = s; c4[w] = cc; p4[w] = ps; }
  __syncthreads();
  if (tid == 0) {
    float denom  = s4[0] + s4[1] + s4[2] + s4[3];
    float ccsum  = c4[0] + c4[1] + c4[2] + c4[3];
    float possum = p4[0] + p4[1] + p4[2] + p4[3];
    float contrast = logf(denom) - possum / ((float)BS * TEMP);
    out[0] = contrast - 6.0f * ccsum / (float)BS;
  }
}

}  // namespace

extern "C" void kernel_launch(void* const* d_in, const int* in_sizes, int n_in,
                              void* d_out, int out_size, void* d_ws, size_t ws_size,
                              hipStream_t stream) {
  const float* queue  = (const float*)d_in[3];  // [2][QL][DIM]
  const float* proto  = (const float*)d_in[4];  // [K][DIM]
  const float* output = (const float*)d_in[5];  // [2*BS][K]
  const float* emb    = (const float*)d_in[6];  // [2*BS][DIM]
  float* ws = (float*)d_ws;
  ushort* M2   = (ushort*)(ws + OFF_M);
  float* S     = ws + OFF_S;
  int* cnt     = (int*)(ws + OFF_CNT);
  int* offa    = (int*)(ws + OFF_OFFA);
  int* cur     = (int*)(ws + OFF_CUR);
  float* v2    = ws + OFF_V;
  int* hardq   = (int*)(ws + OFF_HQ);
  int* negq    = (int*)(ws + OFF_NQ);
  float* ccpart = ws + OFF_CCP;
  float* pospart = ws + OFF_PSP;
  int* bucket  = (int*)(ws + OFF_BUCKET);
  float* partial = ws + OFF_PART;
  ushort* cvt  = (ushort*)(ws + OFF_CVT);
  float* outc  = ws + OFF_OUTC;
  float* out   = (float*)d_out;

  // single fused zero: S(6KP) + cnt(3008) + offa(3072) + cur(3008) — contiguous
  hipMemsetAsync(S, 0, (6 * KP + 3008 + 3072 + 3008) * sizeof(float), stream);

  k_pre<<<2670 + BS, 256, 0, stream>>>(queue, proto, emb, cvt, outc, pospart);

  // both crops' GEMM + initsample (64 rows/block), one launch
  k_gemm_init<<<1440 + 192, 256, 0, stream>>>(cvt, output, M2, S);

  // sinkhorn: 2 fused iterations, both crops per launch
  k_rowpass_both<<<2 * NTOT, 256, 0, stream>>>(M2, S, v2, 0);           // S1 -> v
  k_colsum_both<<<dim3(3, 2 * NROWG), 256, 0, stream>>>(M2, v2, S, 1);  // v -> S2
  k_rowpass_both<<<2 * NTOT, 256, 0, stream>>>(M2, S, v2, 1);           // S2 -> v
  k_colsum_both<<<dim3(3, 2 * NROWG), 256, 0, stream>>>(M2, v2, S, 2);  // v -> S3

  k_stats_all<<<N2 / 4, 256, 0, stream>>>(output, S, hardq, negq, ccpart);

  k_hist<<<N2 / 256, 256, 0, stream>>>(hardq, cnt);
  k_scan<<<1, 256, 0, stream>>>(cnt, offa);
  k_scatter<<<N2 / 256, 256, 0, stream>>>(hardq, offa, cur, bucket);
  k_denom2<<<NDBLK, 256, 0, stream>>>(outc, negq, offa, bucket, partial);
  k_final<<<1, 256, 0, stream>>>(partial, ccpart, pospart, out);
}

// Round 18
// 191.522 us; speedup vs baseline: 4.2434x; 1.0229x over previous
//
#include <hip/hip_runtime.h>
#include <hip/hip_bf16.h>
#include <cstdint>

namespace {

constexpr int BS   = 2048;
constexpr int DIM  = 256;
constexpr int K    = 3000;
constexpr int K4   = K / 4;        // 750
constexpr int KP   = 3008;         // padded row stride (bf16 matrix)
constexpr int KP4  = KP / 4;       // 752
constexpr int QL   = 3840;
constexpr int NTOT = QL + BS;      // 5888
constexpr int N2   = 2 * BS;       // 4096
constexpr int NDBLK = N2 * 6 / 4;  // 6144
constexpr int NROWG = NTOT / 128;  // 46 colsum row-groups (128 rows each)
constexpr int NIS  = 384;          // initsample blocks (32 rows each, 2 crops)
constexpr float TEMP = 0.2f;
constexpr float INV_EPS = 20.0f;
constexpr float KF = 3000.0f;

// ws layout (float indices)
constexpr size_t OFF_M    = 0;                               // 2 crops of NTOT*KP ushorts
constexpr size_t OFF_S    = OFF_M + (size_t)NTOT * KP;       // 6*KP (S1..S3 x2 crops)
constexpr size_t OFF_CNT  = OFF_S + 6 * KP;                  // 3008 ints
constexpr size_t OFF_OFFA = OFF_CNT + 3008;                  // 3072 ints
constexpr size_t OFF_CUR  = OFF_OFFA + 3072;                 // 3008 ints
constexpr size_t OFF_V    = OFF_CUR + 3008;                  // 2*NTOT
constexpr size_t OFF_HQ   = OFF_V + 2 * NTOT;                // N2 ints
constexpr size_t OFF_NQ   = OFF_HQ + N2;                     // N2*6 ints
constexpr size_t OFF_CCP  = OFF_NQ + (size_t)N2 * 6;         // BS
constexpr size_t OFF_PSP  = OFF_CCP + BS;                    // BS
constexpr size_t OFF_BUCKET = OFF_PSP + BS;                  // N2
constexpr size_t OFF_PART = OFF_BUCKET + N2;                 // NDBLK
constexpr size_t OFF_CVT  = ((OFF_PART + NDBLK + 15) / 16) * 16;
constexpr size_t OFF_OUTC = OFF_CVT + (size_t)(2 * QL + K) * DIM / 2;

using bf16x8 = __attribute__((ext_vector_type(8))) short;
using f32x4  = __attribute__((ext_vector_type(4))) float;
typedef unsigned int uint32;

__device__ __forceinline__ float wave_sum(float v) {
#pragma unroll
  for (int off = 32; off > 0; off >>= 1) v += __shfl_down(v, off, 64);
  return v;
}
__device__ __forceinline__ float wave_max_all(float v) {
#pragma unroll
  for (int off = 32; off > 0; off >>= 1) v = fmaxf(v, __shfl_xor(v, off, 64));
  return v;
}
__device__ __forceinline__ uint32 wave_min_u32_all(uint32 v) {
#pragma unroll
  for (int off = 32; off > 0; off >>= 1) {
    uint32 o = __shfl_xor(v, off, 64);
    v = o < v ? o : v;
  }
  return v;
}
__device__ __forceinline__ uint32 wave_max_u32(uint32 v) {
#pragma unroll
  for (int off = 32; off > 0; off >>= 1) {
    uint32 o = __shfl_down(v, off, 64);
    v = o > v ? o : v;
  }
  return v;
}
__device__ __forceinline__ uint32 fmono(float f) {
  uint32 u = __float_as_uint(f);
  return (u & 0x80000000u) ? ~u : (u | 0x80000000u);
}
__device__ __forceinline__ float bf2f(short s) {
  return __uint_as_float(((uint32)(unsigned short)s) << 16);
}
__device__ __forceinline__ ushort f2bf(float f) {
  __hip_bfloat16 b = __float2bfloat16(f);
  return *reinterpret_cast<ushort*>(&b);
}

// -------- fused preprocessing: convert queue+proto to bf16, normalize emb + pos dot --------
__global__ __launch_bounds__(256) void k_pre(
    const float* __restrict__ queue, const float* __restrict__ proto,
    const float* __restrict__ emb, ushort* __restrict__ cvt,
    float* __restrict__ outc, float* __restrict__ pospart) {
  const int bid = blockIdx.x, tid = threadIdx.x;
  if (bid < 1920) {
    int i = bid * 256 + tid;
    float4 v = reinterpret_cast<const float4*>(queue)[i];
    ushort4 h;
    h.x = f2bf(v.x); h.y = f2bf(v.y); h.z = f2bf(v.z); h.w = f2bf(v.w);
    reinterpret_cast<ushort4*>(cvt)[i] = h;
  } else if (bid < 2670) {
    int i = (bid - 1920) * 256 + tid;
    float4 v = reinterpret_cast<const float4*>(proto)[i];
    ushort4 h;
    h.x = f2bf(v.x); h.y = f2bf(v.y); h.z = f2bf(v.z); h.w = f2bf(v.w);
    reinterpret_cast<ushort4*>(cvt + (size_t)2 * QL * DIM)[i] = h;
  } else {
    __shared__ float sa[4], sb[4], sd[4];
    __shared__ float na, nb;
    const int j = bid - 2670, t = tid;
    float za = emb[(size_t)(BS + j) * DIM + t] / TEMP;
    float zb = emb[(size_t)j * DIM + t] / TEMP;
    float ra = wave_sum(za * za);
    float rb = wave_sum(zb * zb);
    if ((t & 63) == 0) { sa[t >> 6] = ra; sb[t >> 6] = rb; }
    __syncthreads();
    if (t == 0) {
      na = sqrtf(sa[0] + sa[1] + sa[2] + sa[3]);
      nb = sqrtf(sb[0] + sb[1] + sb[2] + sb[3]);
    }
    __syncthreads();
    float oa = za / na, ob = zb / nb;
    outc[(size_t)j * DIM + t] = oa;
    outc[(size_t)(BS + j) * DIM + t] = ob;
    float d = wave_sum(oa * ob);
    if ((t & 63) == 0) sd[t >> 6] = d;
    __syncthreads();
    if (t == 0) pospart[j] = sd[0] + sd[1] + sd[2] + sd[3];
  }
}

// -------- fused: initsample FIRST (blocks 0..383, 32 rows each) then
//          both crops' GEMM (blocks 384..1823) --------
__global__ __launch_bounds__(256) void k_gemm_init(
    const ushort* __restrict__ cvt, const float* __restrict__ output,
    ushort* __restrict__ M2, float* __restrict__ S) {
  __shared__ ushort smem[10240] __attribute__((aligned(16)));  // 20480 B
  const int bid = blockIdx.x;
  const int tid = threadIdx.x;
  if (bid >= NIS) {
    ushort (*Ah)[40] = reinterpret_cast<ushort(*)[40]>(smem);
    ushort (*Bh)[40] = reinterpret_cast<ushort(*)[40]>(smem + 5120);
    ushort (*tile64)[136] = reinterpret_cast<ushort(*)[136]>(smem);
    const int gb = bid - NIS;
    const int crop = gb / 720, rem = gb % 720;
    const int bn0 = (rem % 24) * 128;
    const int bm0 = (rem / 24) * 128;
    const ushort* A_g = cvt + (size_t)crop * QL * DIM;
    const ushort* B_g = cvt + (size_t)2 * QL * DIM;
    ushort* M = M2 + (size_t)crop * NTOT * KP;
    float* S1 = S + (size_t)crop * 3 * KP;
    const int wid  = tid >> 6, lane = tid & 63;
    const int wm0  = (wid >> 1) * 64, wn0 = (wid & 1) * 64;
    const int ln15 = lane & 15, lq = lane >> 4;
    const int lr   = tid >> 2;
    const int lc   = (tid & 3) * 8;
    const int brow0 = (bn0 + lr >= K) ? (K - 1) : (bn0 + lr);
    const int brow1 = (bn0 + 64 + lr >= K) ? (K - 1) : (bn0 + 64 + lr);

    f32x4 acc[4][4] = {};
    bf16x8 ra0, ra1, rb0, rb1;
    ra0 = *reinterpret_cast<const bf16x8*>(&A_g[(size_t)(bm0 + lr) * DIM + lc]);
    ra1 = *reinterpret_cast<const bf16x8*>(&A_g[(size_t)(bm0 + 64 + lr) * DIM + lc]);
    rb0 = *reinterpret_cast<const bf16x8*>(&B_g[(size_t)brow0 * DIM + lc]);
    rb1 = *reinterpret_cast<const bf16x8*>(&B_g[(size_t)brow1 * DIM + lc]);

    for (int it = 0; it < 8; ++it) {
      *reinterpret_cast<bf16x8*>(&Ah[lr][lc]) = ra0;
      *reinterpret_cast<bf16x8*>(&Ah[64 + lr][lc]) = ra1;
      *reinterpret_cast<bf16x8*>(&Bh[lr][lc]) = rb0;
      *reinterpret_cast<bf16x8*>(&Bh[64 + lr][lc]) = rb1;
      __syncthreads();
      if (it < 7) {
        const int kk = (it + 1) * 32;
        ra0 = *reinterpret_cast<const bf16x8*>(&A_g[(size_t)(bm0 + lr) * DIM + kk + lc]);
        ra1 = *reinterpret_cast<const bf16x8*>(&A_g[(size_t)(bm0 + 64 + lr) * DIM + kk + lc]);
        rb0 = *reinterpret_cast<const bf16x8*>(&B_g[(size_t)brow0 * DIM + kk + lc]);
        rb1 = *reinterpret_cast<const bf16x8*>(&B_g[(size_t)brow1 * DIM + kk + lc]);
      }
      bf16x8 ah[4], bh[4];
#pragma unroll
      for (int i = 0; i < 4; ++i) {
        ah[i] = *reinterpret_cast<const bf16x8*>(&Ah[wm0 + i * 16 + ln15][lq * 8]);
        bh[i] = *reinterpret_cast<const bf16x8*>(&Bh[wn0 + i * 16 + ln15][lq * 8]);
      }
#pragma unroll
      for (int i = 0; i < 4; ++i)
#pragma unroll
        for (int j = 0; j < 4; ++j)
          acc[i][j] = __builtin_amdgcn_mfma_f32_16x16x32_bf16(ah[i], bh[j], acc[i][j], 0, 0, 0);
      __syncthreads();
    }

    // epilogue: two 64-row halves through tile64 (aliases staging LDS)
    const int rw = tid >> 4;
    const int c8 = (tid & 15) * 8;
    const bool colOk = (bn0 + c8) < KP;
#pragma unroll
    for (int h = 0; h < 2; ++h) {
      if ((wid >> 1) == h) {
#pragma unroll
        for (int j = 0; j < 4; ++j) {
          int col = bn0 + wn0 + j * 16 + ln15;
          bool valid = col < K;
          float csum = 0.f;
#pragma unroll
          for (int i = 0; i < 4; ++i) {
            int rowb = i * 16 + lq * 4;
#pragma unroll
            for (int r = 0; r < 4; ++r) {
              float q = valid ? __expf(acc[i][j][r] * INV_EPS) : 0.f;
              tile64[rowb + r][wn0 + j * 16 + ln15] = f2bf(q);
              csum += q;
            }
          }
          csum += __shfl_xor(csum, 16, 64);
          csum += __shfl_xor(csum, 32, 64);
          if (lane < 16 && valid) atomicAdd(&S1[col], csum);
        }
      }
      __syncthreads();
      if (colOk) {
#pragma unroll
        for (int pass = 0; pass < 4; ++pass) {
          int row = pass * 16 + rw;
          *reinterpret_cast<bf16x8*>(&M[(size_t)(bm0 + h * 64 + row) * KP + bn0 + c8]) =
              *reinterpret_cast<const bf16x8*>(&tile64[row][c8]);
        }
      }
      __syncthreads();
    }
  } else {
    // initsample: 32 rows per block, dispatched FIRST so they overlap GEMM
    const int crop = bid / 192, rem = bid % 192;
    const float* outCrop = output + (size_t)crop * BS * K;
    ushort* M = M2 + (size_t)crop * NTOT * KP;
    float* S1 = S + (size_t)crop * 3 * KP;
    int k4 = (rem % 3) * 256 + tid;
    int r0 = (rem / 3) * 32;
    if (k4 >= KP4) return;
    bool pad = k4 >= K4;
    float ax = 0.f, ay = 0.f, az = 0.f, aw = 0.f;
    for (int rr = 0; rr < 32; ++rr) {
      int row = r0 + rr;
      ushort4 w = make_ushort4(0, 0, 0, 0);
      if (!pad) {
        float4 x = reinterpret_cast<const float4*>(outCrop + (size_t)row * K)[k4];
        float ex = __expf(x.x * INV_EPS), ey = __expf(x.y * INV_EPS),
              ez = __expf(x.z * INV_EPS), ew = __expf(x.w * INV_EPS);
        ax += ex; ay += ey; az += ez; aw += ew;
        w.x = f2bf(ex); w.y = f2bf(ey); w.z = f2bf(ez); w.w = f2bf(ew);
      }
      reinterpret_cast<ushort4*>(M + (size_t)(QL + row) * KP)[k4] = w;
    }
    if (!pad) {
      atomicAdd(&S1[k4 * 4 + 0], ax);
      atomicAdd(&S1[k4 * 4 + 1], ay);
      atomicAdd(&S1[k4 * 4 + 2], az);
      atomicAdd(&S1[k4 * 4 + 3], aw);
    }
  }
}

// -------- rowpass both crops: v[n] = 1/(NTOT * sum_k M[n][k]/(K*S_in[k])) --------
__global__ __launch_bounds__(256) void k_rowpass_both(
    const ushort* __restrict__ M2, const float* __restrict__ S, float* __restrict__ v2,
    int which) {
  __shared__ float red[4];
  const int tid = threadIdx.x;
  const int bid = blockIdx.x;
  const int crop = bid >= NTOT ? 1 : 0;
  const int n = bid - crop * NTOT;
  const ushort* row = M2 + (size_t)crop * NTOT * KP + (size_t)n * KP;
  const float* S_in = S + (size_t)crop * 3 * KP + (size_t)which * KP;
  float* v = v2 + (size_t)crop * NTOT;
  const int g1 = tid, g2 = tid + 256;
  const bool has2 = g2 < KP / 8;
  const bool pad2 = has2 && (g2 == 375);

  float ua[8], ub[8];
  {
    float4 s0 = reinterpret_cast<const float4*>(S_in)[g1 * 2];
    float4 s1 = reinterpret_cast<const float4*>(S_in)[g1 * 2 + 1];
    ua[0] = 1.0f / (KF * s0.x); ua[1] = 1.0f / (KF * s0.y);
    ua[2] = 1.0f / (KF * s0.z); ua[3] = 1.0f / (KF * s0.w);
    ua[4] = 1.0f / (KF * s1.x); ua[5] = 1.0f / (KF * s1.y);
    ua[6] = 1.0f / (KF * s1.z); ua[7] = 1.0f / (KF * s1.w);
  }
  if (has2 && !pad2) {
    float4 s0 = reinterpret_cast<const float4*>(S_in)[g2 * 2];
    float4 s1 = reinterpret_cast<const float4*>(S_in)[g2 * 2 + 1];
    ub[0] = 1.0f / (KF * s0.x); ub[1] = 1.0f / (KF * s0.y);
    ub[2] = 1.0f / (KF * s0.z); ub[3] = 1.0f / (KF * s0.w);
    ub[4] = 1.0f / (KF * s1.x); ub[5] = 1.0f / (KF * s1.y);
    ub[6] = 1.0f / (KF * s1.z); ub[7] = 1.0f / (KF * s1.w);
  } else {
#pragma unroll
    for (int e = 0; e < 8; ++e) ub[e] = 0.f;
  }

  float s = 0.f;
  {
    bf16x8 a = *reinterpret_cast<const bf16x8*>(&row[g1 * 8]);
#pragma unroll
    for (int e = 0; e < 8; ++e) s += bf2f(a[e]) * ua[e];
    if (has2) {
      bf16x8 c = *reinterpret_cast<const bf16x8*>(&row[g2 * 8]);
#pragma unroll
      for (int e = 0; e < 8; ++e) s += bf2f(c[e]) * ub[e];
    }
  }
  s = wave_sum(s);
  if ((tid & 63) == 0) red[tid >> 6] = s;
  __syncthreads();
  if (tid == 0) v[n] = 1.0f / ((float)NTOT * (red[0] + red[1] + red[2] + red[3]));
}

// -------- colsum both crops: 128 rows per block --------
__global__ __launch_bounds__(256) void k_colsum_both(
    const ushort* __restrict__ M2, const float* __restrict__ v2, float* __restrict__ S,
    int which) {
  __shared__ float vsh[128];
  const int tid = threadIdx.x;
  const int crop = blockIdx.y >= NROWG ? 1 : 0;
  const int yy = blockIdx.y - crop * NROWG;
  const ushort* M = M2 + (size_t)crop * NTOT * KP;
  const float* v = v2 + (size_t)crop * NTOT;
  float* S_out = S + (size_t)crop * 3 * KP + (size_t)which * KP;
  const int g = blockIdx.x * 256 + tid;
  const int n0 = yy * 128;
  if (tid < 128) vsh[tid] = v[n0 + tid];
  __syncthreads();
  if (g >= KP4) return;
  float c0 = 0.f, c1 = 0.f, c2 = 0.f, c3 = 0.f;
#pragma unroll 8
  for (int rr = 0; rr < 128; ++rr) {
    ushort4 m = reinterpret_cast<const ushort4*>(M + (size_t)(n0 + rr) * KP)[g];
    float vr = vsh[rr];
    c0 += bf2f((short)m.x) * vr;
    c1 += bf2f((short)m.y) * vr;
    c2 += bf2f((short)m.z) * vr;
    c3 += bf2f((short)m.w) * vr;
  }
  atomicAdd(&S_out[g * 4 + 0], c0);
  atomicAdd(&S_out[g * 4 + 1], c1);
  atomicAdd(&S_out[g * 4 + 2], c2);
  atomicAdd(&S_out[g * 4 + 3], c3);
}

// -------- BOTH crops, one wave per row: hard_q, neg_q, cc partial (inline logu) --------
__global__ __launch_bounds__(256, 4) void k_stats_all(
    const float* __restrict__ outputAll, const float* __restrict__ S,
    int* __restrict__ hardq, int* __restrict__ negq, float* __restrict__ ccpart) {
  const int tid = threadIdx.x;
  const int lane = tid & 63, wid = tid >> 6;
  const int t = blockIdx.x * 4 + wid;
  const int crop = t >> 11;
  const float4* orow4 = reinterpret_cast<const float4*>(outputAll + (size_t)t * K);
  const float4* srow4 = reinterpret_cast<const float4*>(S + (size_t)crop * 3 * KP + 2 * KP);

  float4 o[12], l[12];
#pragma unroll
  for (int e = 0; e < 12; ++e) {
    const int g = lane + 64 * e;
    const bool valid = (e < 11) || (lane < 46);
    o[e] = valid ? orow4[g] : make_float4(0.f, 0.f, 0.f, 0.f);
  }
#pragma unroll
  for (int e = 0; e < 12; ++e) {
    const int g = lane + 64 * e;
    const bool valid = (e < 11) || (lane < 46);
    l[e] = valid ? srow4[g] : make_float4(1.f, 1.f, 1.f, 1.f);
  }

  float4 r4[12];
#pragma unroll
  for (int e = 0; e < 12; ++e) {
    r4[e].x = fmaf(o[e].x, INV_EPS, -__logf(KF * l[e].x));
    r4[e].y = fmaf(o[e].y, INV_EPS, -__logf(KF * l[e].y));
    r4[e].z = fmaf(o[e].z, INV_EPS, -__logf(KF * l[e].z));
    r4[e].w = fmaf(o[e].w, INV_EPS, -__logf(KF * l[e].w));
  }

  uint32 lmin = 0xFFFFFFFFu;
  uint32 am = 0u;
#pragma unroll
  for (int e = 0; e < 12; ++e) {
    const int g = lane + 64 * e;
    const bool valid = (e < 11) || (lane < 46);
    if (valid) {
      const int k0 = g * 4;
      uint32 mx0 = fmono(r4[e].x) & 0xFFFFF000u;
      uint32 mx1 = fmono(r4[e].y) & 0xFFFFF000u;
      uint32 mx2 = fmono(r4[e].z) & 0xFFFFF000u;
      uint32 mx3 = fmono(r4[e].w) & 0xFFFFF000u;
      uint32 k00 = mx0 | (uint32)(k0 + 0);
      uint32 k01 = mx1 | (uint32)(k0 + 1);
      uint32 k02 = mx2 | (uint32)(k0 + 2);
      uint32 k03 = mx3 | (uint32)(k0 + 3);
      uint32 n01 = k00 < k01 ? k00 : k01;
      uint32 n23 = k02 < k03 ? k02 : k03;
      uint32 nn = n01 < n23 ? n01 : n23;
      lmin = nn < lmin ? nn : lmin;
      uint32 a0 = mx0 | (uint32)(4095 - (k0 + 0));
      uint32 a1 = mx1 | (uint32)(4095 - (k0 + 1));
      uint32 a2 = mx2 | (uint32)(4095 - (k0 + 2));
      uint32 a3 = mx3 | (uint32)(4095 - (k0 + 3));
      uint32 m01 = a0 > a1 ? a0 : a1;
      uint32 m23 = a2 > a3 ? a2 : a3;
      uint32 mm = m01 > m23 ? m01 : m23;
      am = mm > am ? mm : am;
    }
  }

  uint32 t8;
  {
    uint32 c = lmin, wm = 0;
#pragma unroll
    for (int it = 0; it < 8; ++it) {
      wm = wave_min_u32_all(c);
      if (c == wm) c = 0xFFFFFFFFu;
    }
    t8 = wm;
  }

  uint32 cand[8];
#pragma unroll
  for (int c = 0; c < 8; ++c) cand[c] = 0xFFFFFFFFu;
#pragma unroll
  for (int e = 0; e < 12; ++e) {
    const int g = lane + 64 * e;
    const bool valid = (e < 11) || (lane < 46);
    if (valid) {
      const int k0 = g * 4;
      float rv[4] = {r4[e].x, r4[e].y, r4[e].z, r4[e].w};
#pragma unroll
      for (int c = 0; c < 4; ++c) {
        uint32 key = (fmono(rv[c]) & 0xFFFFF000u) | (uint32)(k0 + c);
        if (key <= t8 && key < cand[7]) {
          cand[7] = key;
#pragma unroll
          for (int q = 7; q > 0; --q)
            if (cand[q] < cand[q - 1]) { uint32 tmp = cand[q]; cand[q] = cand[q - 1]; cand[q - 1] = tmp; }
        }
      }
    }
  }

  uint32 res[6];
#pragma unroll
  for (int it = 0; it < 8; ++it) {
    uint32 head = cand[0];
    uint32 wm = wave_min_u32_all(head);
    if (it >= 2) res[it - 2] = wm;
    if (head == wm) {
      cand[0] = cand[1]; cand[1] = cand[2]; cand[2] = cand[3]; cand[3] = cand[4];
      cand[4] = cand[5]; cand[5] = cand[6]; cand[6] = cand[7]; cand[7] = 0xFFFFFFFFu;
    }
  }

  am = wave_max_u32(am);
  if (lane == 0) {
    hardq[t] = 4095 - (int)(am & 0xFFFu);
#pragma unroll
    for (int c = 0; c < 6; ++c)
      negq[(size_t)t * 6 + c] = (int)(res[c] & 0xFFFu);
  }

  if (crop == 1) {
    const float4* xrow4 = reinterpret_cast<const float4*>(outputAll + (size_t)(t - BS) * K);
    float4 x4[12];
#pragma unroll
    for (int e = 0; e < 12; ++e) {
      const int g = lane + 64 * e;
      const bool valid = (e < 11) || (lane < 46);
      x4[e] = valid ? xrow4[g] : make_float4(-3.4e38f, -3.4e38f, -3.4e38f, -3.4e38f);
    }
    float mx = -3.4e38f;
#pragma unroll
    for (int e = 0; e < 12; ++e)
      mx = fmaxf(mx, fmaxf(fmaxf(x4[e].x, x4[e].y), fmaxf(x4[e].z, x4[e].w)));
    mx = wave_max_all(mx);
    float sk = 0.f, skx = 0.f, se = 0.f;
#pragma unroll
    for (int e = 0; e < 12; ++e) {
      const bool valid = (e < 11) || (lane < 46);
      if (valid) {
        float4 rr = r4[e];
        float4 x = x4[e];
        float q;
        q = __expf(rr.x); sk += q; skx += q * x.x; se += __expf((x.x - mx) * 5.0f);
        q = __expf(rr.y); sk += q; skx += q * x.y; se += __expf((x.y - mx) * 5.0f);
        q = __expf(rr.z); sk += q; skx += q * x.z; se += __expf((x.z - mx) * 5.0f);
        q = __expf(rr.w); sk += q; skx += q * x.w; se += __expf((x.w - mx) * 5.0f);
      }
    }
    sk = wave_sum(sk); skx = wave_sum(skx); se = wave_sum(se);
    if (lane == 0) {
      float lse = mx * 5.0f + __logf(se);
      ccpart[t - BS] = skx * 5.0f / sk - lse;
    }
  }
}

// -------- denom via class histogram --------
__global__ __launch_bounds__(256) void k_hist(
    const int* __restrict__ hardq, int* __restrict__ cnt) {
  int j = blockIdx.x * 256 + threadIdx.x;
  atomicAdd(&cnt[hardq[j]], 1);
}

__global__ __launch_bounds__(256) void k_scan(
    const int* __restrict__ cnt, int* __restrict__ offa) {
  __shared__ int wsum[4];
  __shared__ int wpre[4];
  const int tid = threadIdx.x;
  const int lane = tid & 63, wid = tid >> 6;
  const int base = tid * 12;
  int loc[12];
  int s = 0;
#pragma unroll
  for (int t = 0; t < 12; ++t) {
    int idx = base + t;
    int cv = (idx < K) ? cnt[idx] : 0;
    loc[t] = cv; s += cv;
  }
  int vincl = s;
#pragma unroll
  for (int d = 1; d < 64; d <<= 1) {
    int t = __shfl_up(vincl, d, 64);
    if (lane >= d) vincl += t;
  }
  if (lane == 63) wsum[wid] = vincl;
  __syncthreads();
  if (tid == 0) {
    int r = 0;
#pragma unroll
    for (int w = 0; w < 4; ++w) { wpre[w] = r; r += wsum[w]; }
  }
  __syncthreads();
  int run = vincl - s + wpre[wid];
#pragma unroll
  for (int t = 0; t < 12; ++t) {
    int idx = base + t;
    if (idx < K) { offa[idx] = run; run += loc[t]; }
  }
  if (tid == 255) offa[K] = run;
}

__global__ __launch_bounds__(256) void k_scatter(
    const int* __restrict__ hardq, const int* __restrict__ offa,
    int* __restrict__ cur, int* __restrict__ bucket) {
  int j = blockIdx.x * 256 + threadIdx.x;
  int c = hardq[j];
  int p = atomicAdd(&cur[c], 1);
  bucket[offa[c] + p] = j;
}

__global__ __launch_bounds__(256) void k_denom2(
    const float* __restrict__ outc, const int* __restrict__ negq,
    const int* __restrict__ offa, const int* __restrict__ bucket,
    float* __restrict__ partial) {
  __shared__ float s4[4];
  const int tid = threadIdx.x;
  const int wid = tid >> 6, lane = tid & 63;
  const int task = blockIdx.x * 4 + wid;
  const int i = task / 6, slot = task - i * 6;
  const int c = negq[i * 6 + slot];
  const int lo = offa[c];
  const int n = offa[c + 1] - lo;
  float acc = 0.f;
  if (n > 0) {
    const float4 a = reinterpret_cast<const float4*>(outc + (size_t)i * DIM)[lane];
    for (int m = 0; m < n; ++m) {
      int j = bucket[lo + m];
      if (j == i) continue;
      const float4 b = reinterpret_cast<const float4*>(outc + (size_t)j * DIM)[lane];
      float d = a.x * b.x + a.y * b.y + a.z * b.z + a.w * b.w;
      d = wave_sum(d);
      if (lane == 0) acc += __expf(d * 5.0f);
    }
  }
  if (lane == 0) s4[wid] = acc;
  __syncthreads();
  if (tid == 0) partial[blockIdx.x] = s4[0] + s4[1] + s4[2] + s4[3];
}

__global__ __launch_bounds__(256) void k_final(
    const float* __restrict__ partial, const float* __restrict__ ccpart,
    const float* __restrict__ pospart, float* __restrict__ out) {
  __shared__ float s4[4], c4[4], p4[4];
  const int tid = threadIdx.x;
  float s = 0.f, cc = 0.f, ps = 0.f;
  for (int m = tid; m < NDBLK; m += 256) s += partial[m];
  for (int m = tid; m < BS; m += 256) { cc += ccpart[m]; ps += pospart[m]; }
  s = wave_sum(s); cc = wave_sum(cc); ps = wave_sum(ps);
  if ((tid & 63) == 0) { int w = tid >> 6; s4[w] = s; c4[w] = cc; p4[w] = ps; }
  __syncthreads();
  if (tid == 0) {
    float denom  = s4[0] + s4[1] + s4[2] + s4[3];
    float ccsum  = c4[0] + c4[1] + c4[2] + c4[3];
    float possum = p4[0] + p4[1] + p4[2] + p4[3];
    float contrast = logf(denom) - possum / ((float)BS * TEMP);
    out[0] = contrast - 6.0f * ccsum / (float)BS;
  }
}

}  // namespace

extern "C" void kernel_launch(void* const* d_in, const int* in_sizes, int n_in,
                              void* d_out, int out_size, void* d_ws, size_t ws_size,
                              hipStream_t stream) {
  const float* queue  = (const float*)d_in[3];  // [2][QL][DIM]
  const float* proto  = (const float*)d_in[4];  // [K][DIM]
  const float* output = (const float*)d_in[5];  // [2*BS][K]
  const float* emb    = (const float*)d_in[6];  // [2*BS][DIM]
  float* ws = (float*)d_ws;
  ushort* M2   = (ushort*)(ws + OFF_M);
  float* S     = ws + OFF_S;
  int* cnt     = (int*)(ws + OFF_CNT);
  int* offa    = (int*)(ws + OFF_OFFA);
  int* cur     = (int*)(ws + OFF_CUR);
  float* v2    = ws + OFF_V;
  int* hardq   = (int*)(ws + OFF_HQ);
  int* negq    = (int*)(ws + OFF_NQ);
  float* ccpart = ws + OFF_CCP;
  float* pospart = ws + OFF_PSP;
  int* bucket  = (int*)(ws + OFF_BUCKET);
  float* partial = ws + OFF_PART;
  ushort* cvt  = (ushort*)(ws + OFF_CVT);
  float* outc  = ws + OFF_OUTC;
  float* out   = (float*)d_out;

  // single fused zero: S(6KP) + cnt(3008) + offa(3072) + cur(3008) — contiguous
  hipMemsetAsync(S, 0, (6 * KP + 3008 + 3072 + 3008) * sizeof(float), stream);

  k_pre<<<2670 + BS, 256, 0, stream>>>(queue, proto, emb, cvt, outc, pospart);

  // initsample (first, 384 blocks x 32 rows) + both crops' GEMM, one launch
  k_gemm_init<<<NIS + 1440, 256, 0, stream>>>(cvt, output, M2, S);

  // sinkhorn: 2 fused iterations, both crops per launch
  k_rowpass_both<<<2 * NTOT, 256, 0, stream>>>(M2, S, v2, 0);           // S1 -> v
  k_colsum_both<<<dim3(3, 2 * NROWG), 256, 0, stream>>>(M2, v2, S, 1);  // v -> S2
  k_rowpass_both<<<2 * NTOT, 256, 0, stream>>>(M2, S, v2, 1);           // S2 -> v
  k_colsum_both<<<dim3(3, 2 * NROWG), 256, 0, stream>>>(M2, v2, S, 2);  // v -> S3

  k_stats_all<<<N2 / 4, 256, 0, stream>>>(output, S, hardq, negq, ccpart);

  k_hist<<<N2 / 256, 256, 0, stream>>>(hardq, cnt);
  k_scan<<<1, 256, 0, stream>>>(cnt, offa);
  k_scatter<<<N2 / 256, 256, 0, stream>>>(hardq, offa, cur, bucket);
  k_denom2<<<NDBLK, 256, 0, stream>>>(outc, negq, offa, bucket, partial);
  k_final<<<1, 256, 0, stream>>>(partial, ccpart, pospart, out);
}